// Round 5
// baseline (8081.574 us; speedup 1.0000x reference)
//
#include <hip/hip_runtime.h>
#include <stdint.h>

typedef short short8 __attribute__((ext_vector_type(8)));
typedef float floatx4 __attribute__((ext_vector_type(4)));
typedef unsigned long long u64;

__device__ __forceinline__ unsigned short f2bf(float f) {
  union { float f; unsigned int i; } v;
  v.f = f;
  unsigned int r = v.i + 0x7fffu + ((v.i >> 16) & 1u);
  return (unsigned short)(r >> 16);
}
__device__ __forceinline__ short8 cvt8(const float4 a, const float4 b) {
  short8 v;
  v[0] = (short)f2bf(a.x); v[1] = (short)f2bf(a.y);
  v[2] = (short)f2bf(a.z); v[3] = (short)f2bf(a.w);
  v[4] = (short)f2bf(b.x); v[5] = (short)f2bf(b.y);
  v[6] = (short)f2bf(b.z); v[7] = (short)f2bf(b.w);
  return v;
}
// NaN-killing clamp: fmaxf(NaN, lo) == lo (v_max_f32, IEEE mode).
__device__ __forceinline__ float sane(float x, float lim) {
  return fminf(fmaxf(x, -lim), lim);
}

extern __shared__ unsigned short lds[];

// ---------------------------------------------------------------------------
// Phase A: gx GEMM.  gx[dir][m][n] = sum_k bf16(A[m][k]) * bf16(wx_dir[n][k])
// (f32 accum, K ascending in 32-chunks with mfma_16x16x32_bf16 -> bitwise
// identical to the recurrence's former in-loop gx chain).  m = t*32 + b.
// XM=1: A = x f32 [B][S][512] (row m -> x[m&31][m>>5]), K=512.
// XM=0: A = y0 bf16 [S*B][1024] row-major, K=1024.
// 128x128 tile, 256 thr (4 waves, 2x2 of 64x64), single-buffered LDS.
// ---------------------------------------------------------------------------
template<int K, int XM>
__global__ __launch_bounds__(256)
void gx_gemm(const float* __restrict__ xf,
             const unsigned short* __restrict__ xb,
             const float* __restrict__ wxf,
             const float* __restrict__ wxb,
             float* __restrict__ gx)
{
  unsigned short* As = lds;              // [128][40] bf16
  unsigned short* Bs = lds + 128 * 40;   // [128][40] bf16

  const int M0 = blockIdx.x * 128;
  const int N0 = blockIdx.y * 128;
  const int dir = blockIdx.z;
  const float* wx = dir ? wxb : wxf;
  float* gxd = gx + (long)dir * 16384 * 1536;

  const int tid = threadIdx.x;
  const int lane = tid & 63;
  const int wid = tid >> 6;
  const int q = lane >> 4;
  const int l16 = lane & 15;
  const int wM = (wid >> 1) * 64;
  const int wN = (wid & 1) * 64;

  const int srow = tid >> 1;             // 0..127 staged row
  const int k0 = (tid & 1) * 16;         // half of the 32-wide K-chunk

  floatx4 acc[4][4];
#pragma unroll
  for (int i = 0; i < 4; ++i)
#pragma unroll
    for (int j = 0; j < 4; ++j) acc[i][j] = (floatx4){0.f, 0.f, 0.f, 0.f};

  for (int kk = 0; kk < K; kk += 32) {
    __syncthreads();
    {
      const int mg = M0 + srow;
      if (XM) {
        const float* ap = xf + ((long)(mg & 31) * 512 + (mg >> 5)) * 512 + kk + k0;
        float4 f0 = *(const float4*)(ap);
        float4 f1 = *(const float4*)(ap + 4);
        float4 f2 = *(const float4*)(ap + 8);
        float4 f3 = *(const float4*)(ap + 12);
        *(short8*)(As + srow * 40 + k0)     = cvt8(f0, f1);
        *(short8*)(As + srow * 40 + k0 + 8) = cvt8(f2, f3);
      } else {
        const unsigned short* ap = xb + (long)mg * 1024 + kk + k0;
        *(short8*)(As + srow * 40 + k0)     = *(const short8*)(ap);
        *(short8*)(As + srow * 40 + k0 + 8) = *(const short8*)(ap + 8);
      }
      const float* bp = wx + (long)(N0 + srow) * K + kk + k0;
      float4 g0 = *(const float4*)(bp);
      float4 g1 = *(const float4*)(bp + 4);
      float4 g2 = *(const float4*)(bp + 8);
      float4 g3 = *(const float4*)(bp + 12);
      *(short8*)(Bs + srow * 40 + k0)     = cvt8(g0, g1);
      *(short8*)(Bs + srow * 40 + k0 + 8) = cvt8(g2, g3);
    }
    __syncthreads();
    short8 a[4], b[4];
#pragma unroll
    for (int mt = 0; mt < 4; ++mt)
      a[mt] = *(const short8*)(As + (wM + mt * 16 + l16) * 40 + q * 8);
#pragma unroll
    for (int nt = 0; nt < 4; ++nt)
      b[nt] = *(const short8*)(Bs + (wN + nt * 16 + l16) * 40 + q * 8);
#pragma unroll
    for (int mt = 0; mt < 4; ++mt)
#pragma unroll
      for (int nt = 0; nt < 4; ++nt)
        acc[mt][nt] = __builtin_amdgcn_mfma_f32_16x16x32_bf16(
            a[mt], b[nt], acc[mt][nt], 0, 0, 0);
  }
#pragma unroll
  for (int mt = 0; mt < 4; ++mt) {
    const int row = M0 + wM + mt * 16 + q * 4;
#pragma unroll
    for (int nt = 0; nt < 4; ++nt) {
      const int col = N0 + wN + nt * 16 + l16;
#pragma unroll
      for (int r = 0; r < 4; ++r)
        gxd[(long)(row + r) * 1536 + col] = acc[mt][nt][r];
    }
  }
}

// ---------------------------------------------------------------------------
// Phase B: persistent recurrence.  32 blocks x 128 thr: 0..15 fw, 16..31 bw.
// Block owns 32 hidden cols; only wh in LDS: whs [96][520] bf16 (99.8 KB).
// gx precomputed f32 [2][S][B][1536].
//
// Exchange: fragment-ordered ring (R4) + bit14 tag protocol (R2).
// R5 changes (counter-driven):
//  (a) retry sweeps now use the SAME lane-contiguous nt b128 loads as the
//      initial read (R4 left retries as the 8B-atomic storm -> steady state
//      was still R3's fabric DDoS; only the never-succeeding first read got
//      coalesced).  Every 4th sweep falls back to agent atomics as a
//      liveness backstop.  A memory-clobber asm in the loop body stops LICM
//      from hoisting the non-volatile nt loads (which would silently
//      degrade progress to the atomic-only path).
//  (b) gx prefetch is issued AFTER tag validation succeeds (pinned by a
//      memory clobber), not between ring loads and sweep: in-order vmcnt
//      retirement otherwise makes every first retry wait out the gx HBM
//      latency (~1us/step of pure serialization in R4).
// ---------------------------------------------------------------------------
template<int OUT>
__global__ __launch_bounds__(128)
void gru_rec(const float* __restrict__ gx,
             const float* __restrict__ whfp, const float* __restrict__ bhfp,
             const float* __restrict__ whbp, const float* __restrict__ bhbp,
             const float* __restrict__ bxfp, const float* __restrict__ bxbp,
             unsigned short* __restrict__ ring,   // [2][2][2][16][64][8], zeroed
             unsigned short* __restrict__ y0,
             float* __restrict__ omain,
             float* __restrict__ out_hf,          // float [32][512]
             float* __restrict__ out_hb)          // float [32][512]
{
  constexpr u64 TM = 0x4000400040004000ULL;       // bit14 of each bf16
  unsigned short* whs = lds;                      // [96][520]

  const int bid = blockIdx.x;
  const bool fw = bid < 16;
  const int d = fw ? bid : bid - 16;
  const int tid = threadIdx.x;
  const int lane = tid & 63;
  const int w = tid >> 6;
  const int q = lane >> 4;
  const int l16 = lane & 15;

  const float* wh = fw ? whfp : whbp;
  const float* bh = fw ? bhfp : bhbp;
  const float* bx = fw ? bxfp : bxbp;
  const int col0 = d * 32;
  const int dirofs = fw ? 0 : 512;
  const long dirbyte = fw ? 0 : 32768;
  const float* gxd = gx + (long)(fw ? 0 : 1) * 16384 * 1536;

  // stage whs: row lr = g*32 + jc  <-  wh row g*512 + col0 + jc (K=512)
  for (int c = tid; c < 96 * 64; c += 128) {
    int lr = c >> 6, c8 = (c & 63) * 8;
    int g = lr >> 5, jc = lr & 31;
    const float* src = wh + (long)(g * 512 + col0 + jc) * 512 + c8;
    *(short8*)(whs + lr * 520 + c8) =
        cvt8(*(const float4*)src, *(const float4*)(src + 4));
  }
  __syncthreads();

  const int jj = l16;
  float cr[2], cz[2], bxn[2], bhn[2];
#pragma unroll
  for (int n2 = 0; n2 < 2; ++n2) {
    const int cc = col0 + n2 * 16 + jj;
    cr[n2] = bx[cc] + bh[cc];
    cz[n2] = bx[512 + cc] + bh[512 + cc];
    bxn[n2] = bx[1024 + cc];
    bhn[n2] = bh[1024 + cc];
  }

  const int cb = w * 16 + q * 4;      // C-layout batch base
  const floatx4 fz = {0.f, 0.f, 0.f, 0.f};
  float h[2][4] = {{0.f, 0.f, 0.f, 0.f}, {0.f, 0.f, 0.f, 0.f}};
  unsigned int* y032 = (unsigned int*)y0;

  // gx prefetch registers: [g][n2][r] -> 24 floats, one step ahead.
  float nx[24];
  auto load_gx = [&](int t) {
    const float* base = gxd + (long)t * 32 * 1536;
#pragma unroll
    for (int g = 0; g < 3; ++g)
#pragma unroll
      for (int n2 = 0; n2 < 2; ++n2)
#pragma unroll
        for (int r = 0; r < 4; ++r)
          nx[(g * 2 + n2) * 4 + r] = __builtin_nontemporal_load(
              base + (long)(cb + r) * 1536 + g * 512 + col0 + n2 * 16 + jj);
  };
  { const int t0 = fw ? 0 : 511; load_gx(t0); }

  union V { u64 u[2]; short8 s; unsigned int dd[4]; };

  for (int it = 0; it < 512; ++it) {
    const int t = fw ? it : 511 - it;
    float cur[24];
#pragma unroll
    for (int i = 0; i < 24; ++i) cur[i] = nx[i];

    const char* rbase = nullptr;
    u64 expectw = 0;
    if (it > 0) {
      const int slot_r = (it + 1) & 1;          // slot written at it-1
      rbase = (const char*)ring + (long)slot_r * 65536 + dirbyte +
              (long)w * 16384 + (long)lane * 16;
      expectw = ((((it - 1) >> 1) & 1) ^ 1) ? TM : 0ULL;
    }

    // phase 1: 16 lane-contiguous nt b128 loads (1KB per instr per wave).
    // NOTE: nothing else issued here -- retry vmcnt waits must cover ONLY
    // these loads (in-order retirement).
    short8 af[16];
    if (it > 0) {
#pragma unroll
      for (int ks = 0; ks < 16; ++ks)
        af[ks] = __builtin_nontemporal_load((const short8*)(rbase + ks * 1024));
    }

    // phase 2: batched validity sweep with COALESCED nt retries; every 4th
    // sweep uses agent atomics (uncached -> guaranteed-fresh liveness).
    floatx4 ar[2] = {fz, fz}, az[2] = {fz, fz}, an[2] = {fz, fz};
    if (it > 0) {
      int sweep = 0;
      while (true) {
        asm volatile("" ::: "memory");   // force re-execution of loads (LICM)
        u64 bad = 0;
#pragma unroll
        for (int ks = 0; ks < 16; ++ks) {
          V v; v.s = af[ks];
          bad |= ((v.u[0] ^ expectw) | (v.u[1] ^ expectw)) & TM;
        }
        if (bad == 0) break;
        __builtin_amdgcn_s_sleep(1);
        if ((++sweep & 3) == 0) {
#pragma unroll
          for (int ks = 0; ks < 16; ++ks) {
            u64* p = (u64*)(rbase + ks * 1024);
            V v;
            v.u[0] = __hip_atomic_load(p,     __ATOMIC_RELAXED, __HIP_MEMORY_SCOPE_AGENT);
            v.u[1] = __hip_atomic_load(p + 1, __ATOMIC_RELAXED, __HIP_MEMORY_SCOPE_AGENT);
            af[ks] = v.s;
          }
        } else {
#pragma unroll
          for (int ks = 0; ks < 16; ++ks)
            af[ks] = __builtin_nontemporal_load((const short8*)(rbase + ks * 1024));
        }
      }
      // pin gx prefetch issue AFTER validation (keeps it out of sweep waits)
      asm volatile("" ::: "memory");
      if (it < 511) {
        const int tn = fw ? it + 1 : 511 - (it + 1);
        load_gx(tn);
      }
#pragma unroll
      for (int ks = 0; ks < 16; ++ks) {
        V v; v.s = af[ks];
        v.dd[0] &= 0xBFFFBFFFu; v.dd[1] &= 0xBFFFBFFFu;
        v.dd[2] &= 0xBFFFBFFFu; v.dd[3] &= 0xBFFFBFFFu;
        short8 a = v.s;
#pragma unroll
        for (int n2 = 0; n2 < 2; ++n2) {
          short8 vr = *(const short8*)(whs + (n2 * 16 + jj) * 520 + ks * 32 + q * 8);
          short8 vz = *(const short8*)(whs + (32 + n2 * 16 + jj) * 520 + ks * 32 + q * 8);
          short8 vn = *(const short8*)(whs + (64 + n2 * 16 + jj) * 520 + ks * 32 + q * 8);
          ar[n2] = __builtin_amdgcn_mfma_f32_16x16x32_bf16(a, vr, ar[n2], 0, 0, 0);
          az[n2] = __builtin_amdgcn_mfma_f32_16x16x32_bf16(a, vz, az[n2], 0, 0, 0);
          an[n2] = __builtin_amdgcn_mfma_f32_16x16x32_bf16(a, vn, an[n2], 0, 0, 0);
        }
      }
    } else {
      load_gx(fw ? 1 : 510);   // it==0: just prefetch next step's gx
    }

    unsigned short hb16[2][4];
#pragma unroll
    for (int n2 = 0; n2 < 2; ++n2) {
#pragma unroll
      for (int r = 0; r < 4; ++r) {
        const float xr = sane(cur[(0 * 2 + n2) * 4 + r] + ar[n2][r] + cr[n2], 60.f);
        const float xz = sane(cur[(1 * 2 + n2) * 4 + r] + az[n2][r] + cz[n2], 60.f);
        const float rr = 1.f / (1.f + __expf(-xr));
        const float zz = 1.f / (1.f + __expf(-xz));
        const float xn = sane(cur[(2 * 2 + n2) * 4 + r] + bxn[n2] +
                              rr * (an[n2][r] + bhn[n2]), 30.f);
        const float e2 = __expf(-2.f * xn);
        const float nn = (1.f - e2) / (1.f + e2);
        h[n2][r] = (1.f - zz) * nn + zz * h[n2][r];
        hb16[n2][r] = f2bf(h[n2][r]);
      }
    }

    // producer: butterfly-pack (q*4+r)-row x 8-col fragment elements, store
    // as line-contiguous u64 agent atomics into fragment-ordered ring.
    {
      const unsigned short utag = (((it >> 1) & 1) ^ 1) ? 0x4000 : 0;
      const int slot_w = it & 1;
      char* sb = (char*)ring + (long)slot_w * 65536 + dirbyte + (long)w * 16384;
      const int o = l16 >> 3;                 // col octet within n2 group
#pragma unroll
      for (int n2 = 0; n2 < 2; ++n2) {
        const int cb2 = col0 + n2 * 16 + o * 8;
        const int ksq = (cb2 >> 5) * 1024 + ((cb2 >> 3) & 3) * 256;
        u64 lo = 0, hi = 0;
#pragma unroll
        for (int r = 0; r < 4; ++r) {
          int tv = (int)(unsigned short)(hb16[n2][r] | utag);
          int pm = __shfl_xor(tv, 1);
          unsigned int pair = (l16 & 1)
              ? ((unsigned)(pm & 0xffff) | ((unsigned)tv << 16))
              : ((unsigned)(tv & 0xffff) | ((unsigned)pm << 16));
          unsigned int pm2 = (unsigned)__shfl_xor((int)pair, 2);
          unsigned int d0 = (l16 & 2) ? pm2 : pair;
          unsigned int d1 = (l16 & 2) ? pair : pm2;
          unsigned int p0 = (unsigned)__shfl_xor((int)d0, 4);
          unsigned int p1 = (unsigned)__shfl_xor((int)d1, 4);
          unsigned int e0 = (l16 & 4) ? p0 : d0;
          unsigned int e1 = (l16 & 4) ? p1 : d1;
          unsigned int e2 = (l16 & 4) ? d0 : p0;
          unsigned int e3 = (l16 & 4) ? d1 : p1;
          if ((l16 & 3) == r) {
            lo = (u64)e0 | ((u64)e1 << 32);
            hi = (u64)e2 | ((u64)e3 << 32);
          }
        }
        if ((l16 & 4) == 0) {
          u64* p = (u64*)(sb + ksq + (q * 4 + (l16 & 3)) * 16);
          __hip_atomic_store(p,     lo, __ATOMIC_RELAXED, __HIP_MEMORY_SCOPE_AGENT);
          __hip_atomic_store(p + 1, hi, __ATOMIC_RELAXED, __HIP_MEMORY_SCOPE_AGENT);
        }
      }
    }

    if (OUT == 0) {  // y0 bf16 [S][B][1024], untagged pairs, nt stores
#pragma unroll
      for (int n2 = 0; n2 < 2; ++n2) {
        const int colw = (dirofs + col0 + n2 * 16 + jj) >> 1;
#pragma unroll
        for (int r = 0; r < 4; ++r) {
          int v = hb16[n2][r];
          int pm = __shfl_xor(v, 1);
          unsigned int pr = (unsigned)(v & 0xffff) | ((unsigned)(pm & 0xffff) << 16);
          if ((jj & 1) == 0)
            __builtin_nontemporal_store(pr,
                y032 + ((long)t * 32 + cb + r) * 512 + colw);
        }
      }
    }
    if (OUT == 1) {  // omain f32 [B][S][1024], nt stores
#pragma unroll
      for (int n2 = 0; n2 < 2; ++n2)
#pragma unroll
        for (int r = 0; r < 4; ++r)
          __builtin_nontemporal_store(h[n2][r],
              omain + (long)(cb + r) * 524288 + (long)t * 1024 +
              dirofs + col0 + n2 * 16 + jj);
    }
    if (it == 511) {
      float* oh = fw ? out_hf : out_hb;
#pragma unroll
      for (int n2 = 0; n2 < 2; ++n2)
#pragma unroll
        for (int r = 0; r < 4; ++r)
          oh[(cb + r) * 512 + col0 + n2 * 16 + jj] = h[n2][r];
    }
  }
}

// ---------------------------------------------------------------------------
// ws layout (235,143,168 B ~= 224.3 MiB):
//   gx    @ 0          : 201326592  f32  [2][512][32][1536]
//   y0    @ 201326592  : 33554432   bf16 [512][32][1024]  (plain, no tags)
//   ring0 @ 234881024  : 131072     fragment-ordered ring (tagged, zeroed)
//   ring1 @ 235012096  : 131072     fragment-ordered ring (tagged, zeroed)
// d_out (float32): main [32][512][1024] @0, h_fw @16777216, h_bw @16809984.
// ---------------------------------------------------------------------------
extern "C" void kernel_launch(void* const* d_in, const int* in_sizes, int n_in,
                              void* d_out, int out_size, void* d_ws, size_t ws_size,
                              hipStream_t stream)
{
  (void)in_sizes; (void)n_in; (void)out_size; (void)ws_size;

  const float* x    = (const float*)d_in[0];
  const float* wxf0 = (const float*)d_in[1];
  const float* bxf0 = (const float*)d_in[2];
  const float* whf0 = (const float*)d_in[3];
  const float* bhf0 = (const float*)d_in[4];
  const float* wxb0 = (const float*)d_in[5];
  const float* bxb0 = (const float*)d_in[6];
  const float* whb0 = (const float*)d_in[7];
  const float* bhb0 = (const float*)d_in[8];
  const float* wxf1 = (const float*)d_in[9];
  const float* bxf1 = (const float*)d_in[10];
  const float* whf1 = (const float*)d_in[11];
  const float* bhf1 = (const float*)d_in[12];
  const float* wxb1 = (const float*)d_in[13];
  const float* bxb1 = (const float*)d_in[14];
  const float* whb1 = (const float*)d_in[15];
  const float* bhb1 = (const float*)d_in[16];

  char* ws = (char*)d_ws;
  float* gx             = (float*)(ws);
  unsigned short* y0    = (unsigned short*)(ws + 201326592L);
  unsigned short* ring0 = (unsigned short*)(ws + 234881024L);
  unsigned short* ring1 = (unsigned short*)(ws + 235012096L);

  float* out = (float*)d_out;
  float* out_hf0 = out + 16777216L;
  float* out_hf1 = out + 16777216L + 16384L;
  float* out_hb0 = out + 16777216L + 32768L;
  float* out_hb1 = out + 16777216L + 49152L;

  const size_t lds_gemm = (size_t)(2 * 128 * 40) * 2;   // 20,480 B
  const size_t lds_rec  = (size_t)(96 * 520) * 2;       // 99,840 B
  (void)hipFuncSetAttribute((const void*)gru_rec<0>,
                            hipFuncAttributeMaxDynamicSharedMemorySize, (int)lds_rec);
  (void)hipFuncSetAttribute((const void*)gru_rec<1>,
                            hipFuncAttributeMaxDynamicSharedMemorySize, (int)lds_rec);

  // zero only the tagged rings (y0 is plain; gx needs no init)
  hipMemsetAsync(ws + 234881024L, 0, 262144L, stream);

  // L0 phase A: gx0[dir][t*32+b][1536] from x f32
  gx_gemm<512, 1><<<dim3(128, 12, 2), dim3(256), lds_gemm, stream>>>(
      x, nullptr, wxf0, wxb0, gx);
  // L0 phase B: recurrence -> y0 bf16 (+ h outputs), ring0 exchange
  gru_rec<0><<<dim3(32), dim3(128), lds_rec, stream>>>(
      gx, whf0, bhf0, whb0, bhb0, bxf0, bxb0,
      ring0, y0, nullptr, out_hf0, out_hb0);
  // L1 phase A: gx1 from y0 bf16
  gx_gemm<1024, 0><<<dim3(128, 12, 2), dim3(256), lds_gemm, stream>>>(
      nullptr, y0, wxf1, wxb1, gx);
  // L1 phase B: recurrence -> omain f32 (+ h outputs), ring1 exchange
  gru_rec<1><<<dim3(32), dim3(128), lds_rec, stream>>>(
      gx, whf1, bhf1, whb1, bhb1, bxf1, bxb1,
      ring1, nullptr, out, out_hf1, out_hb1);
}

// Round 7
// 6536.338 us; speedup vs baseline: 1.2364x; 1.2364x over previous
//
#include <hip/hip_runtime.h>
#include <stdint.h>

typedef short short8 __attribute__((ext_vector_type(8)));
typedef float floatx4 __attribute__((ext_vector_type(4)));
typedef unsigned long long u64;

__device__ __forceinline__ unsigned short f2bf(float f) {
  union { float f; unsigned int i; } v;
  v.f = f;
  unsigned int r = v.i + 0x7fffu + ((v.i >> 16) & 1u);
  return (unsigned short)(r >> 16);
}
__device__ __forceinline__ short8 cvt8(const float4 a, const float4 b) {
  short8 v;
  v[0] = (short)f2bf(a.x); v[1] = (short)f2bf(a.y);
  v[2] = (short)f2bf(a.z); v[3] = (short)f2bf(a.w);
  v[4] = (short)f2bf(b.x); v[5] = (short)f2bf(b.y);
  v[6] = (short)f2bf(b.z); v[7] = (short)f2bf(b.w);
  return v;
}
// NaN-killing clamp: fmaxf(NaN, lo) == lo (v_max_f32, IEEE mode).
__device__ __forceinline__ float sane(float x, float lim) {
  return fminf(fmaxf(x, -lim), lim);
}

extern __shared__ unsigned short lds[];

// ---------------------------------------------------------------------------
// Phase A: gx GEMM.  gx[dir][m][n] = sum_k bf16(A[m][k]) * bf16(wx_dir[n][k])
// (f32 accum, K ascending in 32-chunks with mfma_16x16x32_bf16 -> bitwise
// identical to the recurrence's former in-loop gx chain).  m = t*32 + b.
// XM=1: A = x f32 [B][S][512] (row m -> x[m&31][m>>5]), K=512.
// XM=0: A = y0 bf16 [S*B][1024] row-major, K=1024.
// 128x128 tile, 256 thr (4 waves, 2x2 of 64x64), single-buffered LDS.
// ---------------------------------------------------------------------------
template<int K, int XM>
__global__ __launch_bounds__(256)
void gx_gemm(const float* __restrict__ xf,
             const unsigned short* __restrict__ xb,
             const float* __restrict__ wxf,
             const float* __restrict__ wxb,
             float* __restrict__ gx)
{
  unsigned short* As = lds;              // [128][40] bf16
  unsigned short* Bs = lds + 128 * 40;   // [128][40] bf16

  const int M0 = blockIdx.x * 128;
  const int N0 = blockIdx.y * 128;
  const int dir = blockIdx.z;
  const float* wx = dir ? wxb : wxf;
  float* gxd = gx + (long)dir * 16384 * 1536;

  const int tid = threadIdx.x;
  const int lane = tid & 63;
  const int wid = tid >> 6;
  const int q = lane >> 4;
  const int l16 = lane & 15;
  const int wM = (wid >> 1) * 64;
  const int wN = (wid & 1) * 64;

  const int srow = tid >> 1;             // 0..127 staged row
  const int k0 = (tid & 1) * 16;         // half of the 32-wide K-chunk

  floatx4 acc[4][4];
#pragma unroll
  for (int i = 0; i < 4; ++i)
#pragma unroll
    for (int j = 0; j < 4; ++j) acc[i][j] = (floatx4){0.f, 0.f, 0.f, 0.f};

  for (int kk = 0; kk < K; kk += 32) {
    __syncthreads();
    {
      const int mg = M0 + srow;
      if (XM) {
        const float* ap = xf + ((long)(mg & 31) * 512 + (mg >> 5)) * 512 + kk + k0;
        float4 f0 = *(const float4*)(ap);
        float4 f1 = *(const float4*)(ap + 4);
        float4 f2 = *(const float4*)(ap + 8);
        float4 f3 = *(const float4*)(ap + 12);
        *(short8*)(As + srow * 40 + k0)     = cvt8(f0, f1);
        *(short8*)(As + srow * 40 + k0 + 8) = cvt8(f2, f3);
      } else {
        const unsigned short* ap = xb + (long)mg * 1024 + kk + k0;
        *(short8*)(As + srow * 40 + k0)     = *(const short8*)(ap);
        *(short8*)(As + srow * 40 + k0 + 8) = *(const short8*)(ap + 8);
      }
      const float* bp = wx + (long)(N0 + srow) * K + kk + k0;
      float4 g0 = *(const float4*)(bp);
      float4 g1 = *(const float4*)(bp + 4);
      float4 g2 = *(const float4*)(bp + 8);
      float4 g3 = *(const float4*)(bp + 12);
      *(short8*)(Bs + srow * 40 + k0)     = cvt8(g0, g1);
      *(short8*)(Bs + srow * 40 + k0 + 8) = cvt8(g2, g3);
    }
    __syncthreads();
    short8 a[4], b[4];
#pragma unroll
    for (int mt = 0; mt < 4; ++mt)
      a[mt] = *(const short8*)(As + (wM + mt * 16 + l16) * 40 + q * 8);
#pragma unroll
    for (int nt = 0; nt < 4; ++nt)
      b[nt] = *(const short8*)(Bs + (wN + nt * 16 + l16) * 40 + q * 8);
#pragma unroll
    for (int mt = 0; mt < 4; ++mt)
#pragma unroll
      for (int nt = 0; nt < 4; ++nt)
        acc[mt][nt] = __builtin_amdgcn_mfma_f32_16x16x32_bf16(
            a[mt], b[nt], acc[mt][nt], 0, 0, 0);
  }
#pragma unroll
  for (int mt = 0; mt < 4; ++mt) {
    const int row = M0 + wM + mt * 16 + q * 4;
#pragma unroll
    for (int nt = 0; nt < 4; ++nt) {
      const int col = N0 + wN + nt * 16 + l16;
#pragma unroll
      for (int r = 0; r < 4; ++r)
        gxd[(long)(row + r) * 1536 + col] = acc[mt][nt][r];
    }
  }
}

// ---------------------------------------------------------------------------
// Phase B: persistent recurrence.  32 blocks x 128 thr: 0..15 fw, 16..31 bw.
// Block owns 32 hidden cols; only wh in LDS: whs [96][520] bf16 (99.8 KB).
// gx precomputed f32 [2][S][B][1536].
//
// Exchange: fragment-ordered ring (R4) + bit14 tag protocol (R2).
// Region per wave w: [ks:16][qq:4][row:16][16B]; producer block d writes
// exactly ks=d; the LAST word it stores per quarter is row15,+8 (offset
// ks*1024 + qq*256 + 248).
// R6 change (single-variable vs R4): CANARY-GATED discovery.  Instead of
// issuing the guaranteed-stale 16KB fragment load at step start and
// re-loading 16KB per retry sweep (R4: discovery quantum = full-reload RT,
// 1MB/step aggregate -> congestion feedback), each wave polls 64 canary
// words (ONE 8B bypass load per (ks,qq), 1 instruction, 64 lines = 1/4 the
// traffic) until all carry this step's tag, THEN issues the full fragment
// load once.  Validate + atomic-reload backstop kept verbatim from R4
// (relaxed stores are unordered; canary is a gate, not a guarantee).
// R6b hardening: canary poll is BOUNDED (8192 iters) then falls through to
// the validate loop (whose atomic-reload path is the proven-terminating
// backstop) -- no new unbounded spin anywhere.
// R5 lesson encoded: nontemporal loads may serve stale cached data -- all
// polling/retry reads here are agent-scope bypass loads.
// ---------------------------------------------------------------------------
template<int OUT>
__global__ __launch_bounds__(128)
void gru_rec(const float* __restrict__ gx,
             const float* __restrict__ whfp, const float* __restrict__ bhfp,
             const float* __restrict__ whbp, const float* __restrict__ bhbp,
             const float* __restrict__ bxfp, const float* __restrict__ bxbp,
             unsigned short* __restrict__ ring,   // [2][2][2][16][64][8], zeroed
             unsigned short* __restrict__ y0,
             float* __restrict__ omain,
             float* __restrict__ out_hf,          // float [32][512]
             float* __restrict__ out_hb)          // float [32][512]
{
  constexpr u64 TM = 0x4000400040004000ULL;       // bit14 of each bf16
  unsigned short* whs = lds;                      // [96][520]

  const int bid = blockIdx.x;
  const bool fw = bid < 16;
  const int d = fw ? bid : bid - 16;
  const int tid = threadIdx.x;
  const int lane = tid & 63;
  const int w = tid >> 6;
  const int q = lane >> 4;
  const int l16 = lane & 15;

  const float* wh = fw ? whfp : whbp;
  const float* bh = fw ? bhfp : bhbp;
  const float* bx = fw ? bxfp : bxbp;
  const int col0 = d * 32;
  const int dirofs = fw ? 0 : 512;
  const long dirbyte = fw ? 0 : 32768;
  const float* gxd = gx + (long)(fw ? 0 : 1) * 16384 * 1536;

  // stage whs: row lr = g*32 + jc  <-  wh row g*512 + col0 + jc (K=512)
  for (int c = tid; c < 96 * 64; c += 128) {
    int lr = c >> 6, c8 = (c & 63) * 8;
    int g = lr >> 5, jc = lr & 31;
    const float* src = wh + (long)(g * 512 + col0 + jc) * 512 + c8;
    *(short8*)(whs + lr * 520 + c8) =
        cvt8(*(const float4*)src, *(const float4*)(src + 4));
  }
  __syncthreads();

  const int jj = l16;
  float cr[2], cz[2], bxn[2], bhn[2];
#pragma unroll
  for (int n2 = 0; n2 < 2; ++n2) {
    const int cc = col0 + n2 * 16 + jj;
    cr[n2] = bx[cc] + bh[cc];
    cz[n2] = bx[512 + cc] + bh[512 + cc];
    bxn[n2] = bx[1024 + cc];
    bhn[n2] = bh[1024 + cc];
  }

  const int cb = w * 16 + q * 4;      // C-layout batch base
  const floatx4 fz = {0.f, 0.f, 0.f, 0.f};
  float h[2][4] = {{0.f, 0.f, 0.f, 0.f}, {0.f, 0.f, 0.f, 0.f}};
  unsigned int* y032 = (unsigned int*)y0;

  // gx prefetch registers: [g][n2][r] -> 24 floats, one step ahead.
  float nx[24];
  auto load_gx = [&](int t) {
    const float* base = gxd + (long)t * 32 * 1536;
#pragma unroll
    for (int g = 0; g < 3; ++g)
#pragma unroll
      for (int n2 = 0; n2 < 2; ++n2)
#pragma unroll
        for (int r = 0; r < 4; ++r)
          nx[(g * 2 + n2) * 4 + r] = __builtin_nontemporal_load(
              base + (long)(cb + r) * 1536 + g * 512 + col0 + n2 * 16 + jj);
  };
  { const int t0 = fw ? 0 : 511; load_gx(t0); }

  union V { u64 u[2]; short8 s; unsigned int dd[4]; };

  for (int it = 0; it < 512; ++it) {
    const int t = fw ? it : 511 - it;
    float cur[24];
#pragma unroll
    for (int i = 0; i < 24; ++i) cur[i] = nx[i];

    // phase 0: issue next-step gx prefetch (HBM latency hides under the
    // producers' store drain + canary poll).
    if (it < 511) {
      const int tn = fw ? it + 1 : 511 - (it + 1);
      load_gx(tn);
    }

    const char* wregion = nullptr;
    const char* rbase = nullptr;
    u64 expectw = 0;
    if (it > 0) {
      const int slot_r = (it + 1) & 1;          // slot written at it-1
      wregion = (const char*)ring + (long)slot_r * 65536 + dirbyte +
                (long)w * 16384;
      rbase = wregion + (long)lane * 16;
      expectw = ((((it - 1) >> 1) & 1) ^ 1) ? TM : 0ULL;
    }

    floatx4 ar[2] = {fz, fz}, az[2] = {fz, fz}, an[2] = {fz, fz};
    if (it > 0) {
      // phase 1: canary poll (BOUNDED).  Lane (q,l16) watches producer
      // ks=l16, quarter qq=q, last-stored word (row15,+8).  One 8B bypass
      // load per lane per iteration; proceed when all 64 canaries carry the
      // tag, or after the bound (validate loop below is the safety net).
      const u64* cptr = (const u64*)(wregion + (long)l16 * 1024 +
                                     (long)q * 256 + 248);
      for (int pc = 0; pc < 8192; ++pc) {
        u64 can = __hip_atomic_load(cptr, __ATOMIC_RELAXED,
                                    __HIP_MEMORY_SCOPE_AGENT);
        if (__ballot(((can ^ expectw) & TM) != 0) == 0) break;
        __builtin_amdgcn_s_sleep(1);
      }

      // phase 2: full fragment load (16 lane-contiguous b128), validate,
      // atomic-reload backstop (R4 verbatim; fires only for stragglers).
      short8 af[16];
#pragma unroll
      for (int ks = 0; ks < 16; ++ks)
        af[ks] = __builtin_nontemporal_load((const short8*)(rbase + ks * 1024));
      while (true) {
        u64 bad = 0;
#pragma unroll
        for (int ks = 0; ks < 16; ++ks) {
          V v; v.s = af[ks];
          bad |= ((v.u[0] ^ expectw) | (v.u[1] ^ expectw)) & TM;
        }
        if (bad == 0) break;
        __builtin_amdgcn_s_sleep(1);
#pragma unroll
        for (int ks = 0; ks < 16; ++ks) {
          u64* p = (u64*)(rbase + ks * 1024);
          V v;
          v.u[0] = __hip_atomic_load(p,     __ATOMIC_RELAXED, __HIP_MEMORY_SCOPE_AGENT);
          v.u[1] = __hip_atomic_load(p + 1, __ATOMIC_RELAXED, __HIP_MEMORY_SCOPE_AGENT);
          af[ks] = v.s;
        }
      }
#pragma unroll
      for (int ks = 0; ks < 16; ++ks) {
        V v; v.s = af[ks];
        v.dd[0] &= 0xBFFFBFFFu; v.dd[1] &= 0xBFFFBFFFu;
        v.dd[2] &= 0xBFFFBFFFu; v.dd[3] &= 0xBFFFBFFFu;
        short8 a = v.s;
#pragma unroll
        for (int n2 = 0; n2 < 2; ++n2) {
          short8 vr = *(const short8*)(whs + (n2 * 16 + jj) * 520 + ks * 32 + q * 8);
          short8 vz = *(const short8*)(whs + (32 + n2 * 16 + jj) * 520 + ks * 32 + q * 8);
          short8 vn = *(const short8*)(whs + (64 + n2 * 16 + jj) * 520 + ks * 32 + q * 8);
          ar[n2] = __builtin_amdgcn_mfma_f32_16x16x32_bf16(a, vr, ar[n2], 0, 0, 0);
          az[n2] = __builtin_amdgcn_mfma_f32_16x16x32_bf16(a, vz, az[n2], 0, 0, 0);
          an[n2] = __builtin_amdgcn_mfma_f32_16x16x32_bf16(a, vn, an[n2], 0, 0, 0);
        }
      }
    }

    unsigned short hb16[2][4];
#pragma unroll
    for (int n2 = 0; n2 < 2; ++n2) {
#pragma unroll
      for (int r = 0; r < 4; ++r) {
        const float xr = sane(cur[(0 * 2 + n2) * 4 + r] + ar[n2][r] + cr[n2], 60.f);
        const float xz = sane(cur[(1 * 2 + n2) * 4 + r] + az[n2][r] + cz[n2], 60.f);
        const float rr = 1.f / (1.f + __expf(-xr));
        const float zz = 1.f / (1.f + __expf(-xz));
        const float xn = sane(cur[(2 * 2 + n2) * 4 + r] + bxn[n2] +
                              rr * (an[n2][r] + bhn[n2]), 30.f);
        const float e2 = __expf(-2.f * xn);
        const float nn = (1.f - e2) / (1.f + e2);
        h[n2][r] = (1.f - zz) * nn + zz * h[n2][r];
        hb16[n2][r] = f2bf(h[n2][r]);
      }
    }

    // producer: butterfly-pack (q*4+r)-row x 8-col fragment elements, store
    // as line-contiguous u64 agent atomics into fragment-ordered ring.
    {
      const unsigned short utag = (((it >> 1) & 1) ^ 1) ? 0x4000 : 0;
      const int slot_w = it & 1;
      char* sb = (char*)ring + (long)slot_w * 65536 + dirbyte + (long)w * 16384;
      const int o = l16 >> 3;                 // col octet within n2 group
#pragma unroll
      for (int n2 = 0; n2 < 2; ++n2) {
        const int cb2 = col0 + n2 * 16 + o * 8;
        const int ksq = (cb2 >> 5) * 1024 + ((cb2 >> 3) & 3) * 256;
        u64 lo = 0, hi = 0;
#pragma unroll
        for (int r = 0; r < 4; ++r) {
          int tv = (int)(unsigned short)(hb16[n2][r] | utag);
          int pm = __shfl_xor(tv, 1);
          unsigned int pair = (l16 & 1)
              ? ((unsigned)(pm & 0xffff) | ((unsigned)tv << 16))
              : ((unsigned)(tv & 0xffff) | ((unsigned)pm << 16));
          unsigned int pm2 = (unsigned)__shfl_xor((int)pair, 2);
          unsigned int d0 = (l16 & 2) ? pm2 : pair;
          unsigned int d1 = (l16 & 2) ? pair : pm2;
          unsigned int p0 = (unsigned)__shfl_xor((int)d0, 4);
          unsigned int p1 = (unsigned)__shfl_xor((int)d1, 4);
          unsigned int e0 = (l16 & 4) ? p0 : d0;
          unsigned int e1 = (l16 & 4) ? p1 : d1;
          unsigned int e2 = (l16 & 4) ? d0 : p0;
          unsigned int e3 = (l16 & 4) ? d1 : p1;
          if ((l16 & 3) == r) {
            lo = (u64)e0 | ((u64)e1 << 32);
            hi = (u64)e2 | ((u64)e3 << 32);
          }
        }
        if ((l16 & 4) == 0) {
          u64* p = (u64*)(sb + ksq + (q * 4 + (l16 & 3)) * 16);
          __hip_atomic_store(p,     lo, __ATOMIC_RELAXED, __HIP_MEMORY_SCOPE_AGENT);
          __hip_atomic_store(p + 1, hi, __ATOMIC_RELAXED, __HIP_MEMORY_SCOPE_AGENT);
        }
      }
    }

    if (OUT == 0) {  // y0 bf16 [S][B][1024], untagged pairs, nt stores
#pragma unroll
      for (int n2 = 0; n2 < 2; ++n2) {
        const int colw = (dirofs + col0 + n2 * 16 + jj) >> 1;
#pragma unroll
        for (int r = 0; r < 4; ++r) {
          int v = hb16[n2][r];
          int pm = __shfl_xor(v, 1);
          unsigned int pr = (unsigned)(v & 0xffff) | ((unsigned)(pm & 0xffff) << 16);
          if ((jj & 1) == 0)
            __builtin_nontemporal_store(pr,
                y032 + ((long)t * 32 + cb + r) * 512 + colw);
        }
      }
    }
    if (OUT == 1) {  // omain f32 [B][S][1024], nt stores
#pragma unroll
      for (int n2 = 0; n2 < 2; ++n2)
#pragma unroll
        for (int r = 0; r < 4; ++r)
          __builtin_nontemporal_store(h[n2][r],
              omain + (long)(cb + r) * 524288 + (long)t * 1024 +
              dirofs + col0 + n2 * 16 + jj);
    }
    if (it == 511) {
      float* oh = fw ? out_hf : out_hb;
#pragma unroll
      for (int n2 = 0; n2 < 2; ++n2)
#pragma unroll
        for (int r = 0; r < 4; ++r)
          oh[(cb + r) * 512 + col0 + n2 * 16 + jj] = h[n2][r];
    }
  }
}

// ---------------------------------------------------------------------------
// ws layout (235,143,168 B ~= 224.3 MiB):
//   gx    @ 0          : 201326592  f32  [2][512][32][1536]
//   y0    @ 201326592  : 33554432   bf16 [512][32][1024]  (plain, no tags)
//   ring0 @ 234881024  : 131072     fragment-ordered ring (tagged, zeroed)
//   ring1 @ 235012096  : 131072     fragment-ordered ring (tagged, zeroed)
// d_out (float32): main [32][512][1024] @0, h_fw @16777216, h_bw @16809984.
// ---------------------------------------------------------------------------
extern "C" void kernel_launch(void* const* d_in, const int* in_sizes, int n_in,
                              void* d_out, int out_size, void* d_ws, size_t ws_size,
                              hipStream_t stream)
{
  (void)in_sizes; (void)n_in; (void)out_size; (void)ws_size;

  const float* x    = (const float*)d_in[0];
  const float* wxf0 = (const float*)d_in[1];
  const float* bxf0 = (const float*)d_in[2];
  const float* whf0 = (const float*)d_in[3];
  const float* bhf0 = (const float*)d_in[4];
  const float* wxb0 = (const float*)d_in[5];
  const float* bxb0 = (const float*)d_in[6];
  const float* whb0 = (const float*)d_in[7];
  const float* bhb0 = (const float*)d_in[8];
  const float* wxf1 = (const float*)d_in[9];
  const float* bxf1 = (const float*)d_in[10];
  const float* whf1 = (const float*)d_in[11];
  const float* bhf1 = (const float*)d_in[12];
  const float* wxb1 = (const float*)d_in[13];
  const float* bxb1 = (const float*)d_in[14];
  const float* whb1 = (const float*)d_in[15];
  const float* bhb1 = (const float*)d_in[16];

  char* ws = (char*)d_ws;
  float* gx             = (float*)(ws);
  unsigned short* y0    = (unsigned short*)(ws + 201326592L);
  unsigned short* ring0 = (unsigned short*)(ws + 234881024L);
  unsigned short* ring1 = (unsigned short*)(ws + 235012096L);

  float* out = (float*)d_out;
  float* out_hf0 = out + 16777216L;
  float* out_hf1 = out + 16777216L + 16384L;
  float* out_hb0 = out + 16777216L + 32768L;
  float* out_hb1 = out + 16777216L + 49152L;

  const size_t lds_gemm = (size_t)(2 * 128 * 40) * 2;   // 20,480 B
  const size_t lds_rec  = (size_t)(96 * 520) * 2;       // 99,840 B
  (void)hipFuncSetAttribute((const void*)gru_rec<0>,
                            hipFuncAttributeMaxDynamicSharedMemorySize, (int)lds_rec);
  (void)hipFuncSetAttribute((const void*)gru_rec<1>,
                            hipFuncAttributeMaxDynamicSharedMemorySize, (int)lds_rec);

  // zero only the tagged rings (y0 is plain; gx needs no init)
  hipMemsetAsync(ws + 234881024L, 0, 262144L, stream);

  // L0 phase A: gx0[dir][t*32+b][1536] from x f32
  gx_gemm<512, 1><<<dim3(128, 12, 2), dim3(256), lds_gemm, stream>>>(
      x, nullptr, wxf0, wxb0, gx);
  // L0 phase B: recurrence -> y0 bf16 (+ h outputs), ring0 exchange
  gru_rec<0><<<dim3(32), dim3(128), lds_rec, stream>>>(
      gx, whf0, bhf0, whb0, bhb0, bxf0, bxb0,
      ring0, y0, nullptr, out_hf0, out_hb0);
  // L1 phase A: gx1 from y0 bf16
  gx_gemm<1024, 0><<<dim3(128, 12, 2), dim3(256), lds_gemm, stream>>>(
      nullptr, y0, wxf1, wxb1, gx);
  // L1 phase B: recurrence -> omain f32 (+ h outputs), ring1 exchange
  gru_rec<1><<<dim3(32), dim3(128), lds_rec, stream>>>(
      gx, whf1, bhf1, whb1, bhb1, bxf1, bxb1,
      ring1, nullptr, out, out_hf1, out_hb1);
}